// Round 5
// baseline (429.868 us; speedup 1.0000x reference)
//
#include <hip/hip_runtime.h>
#include <hip/hip_bf16.h>
#include <math.h>

// Problem constants (from reference)
#define T_ 256
#define B_ 64
#define I_ 1024
#define L_ 2
#define G_ 4
#define H_ 1024
#define R_ 16

#define NBLOCKS 512
#define BAR_MAGIC 0x13572468u

typedef __bf16 bf16x8 __attribute__((ext_vector_type(8)));
typedef float floatx4 __attribute__((ext_vector_type(4)));

__device__ inline bf16x8 cvt_bf16x8(float4 a, float4 b) {
    bf16x8 r;
    r[0] = (__bf16)a.x; r[1] = (__bf16)a.y; r[2] = (__bf16)a.z; r[3] = (__bf16)a.w;
    r[4] = (__bf16)b.x; r[5] = (__bf16)b.y; r[6] = (__bf16)b.z; r[7] = (__bf16)b.w;
    return r;
}

// ---------------------------------------------------------------------------
// Manual grid barrier (sense-free: one fresh counter per phase).
// Writer side: __threadfence (device-scope release of all prior stores) +
// device-scope atomicAdd. Reader side: device-scope acquire load (invalidates
// L1) then proceeds. Counters are zeroed by block 0 at kernel start (ws is
// re-poisoned 0xAA before every call), publish via magic flag.
// ---------------------------------------------------------------------------
__device__ inline void grid_barrier(unsigned* bar, int phase) {
    __syncthreads();
    if (threadIdx.x == 0) {
        __threadfence();
        unsigned* cnt = bar + phase;
        atomicAdd(cnt, 1u);
        while (__hip_atomic_load(cnt, __ATOMIC_ACQUIRE,
                                 __HIP_MEMORY_SCOPE_AGENT) < (unsigned)NBLOCKS) {
            __builtin_amdgcn_s_sleep(1);
        }
    }
    __syncthreads();
}

// ---------------------------------------------------------------------------
// Stage A: split-K MFMA GEMM (batched 16KB W loads per wave) + LoRA t-dots.
//   2048 waves: (nb,kb) = (gid&255, gid>>8); each also does 4 of 8192 t-dots.
//   (verbatim R3 body — passed at absmax 0.015625)
// ---------------------------------------------------------------------------
__device__ inline void gemm_stage(
    const float* __restrict__ Wx_l, const float* __restrict__ Wh_l,
    const float* __restrict__ x_src, const float* __restrict__ h_src,
    const float* __restrict__ A_x_l, const float* __restrict__ A_h_l,
    float* __restrict__ part, float* __restrict__ t_x, float* __restrict__ t_h,
    int gid, int lane)
{
    const int nb = gid & 255;         // 0..255
    const int kb = gid >> 8;          // 0..7
    const float* Wbase = (kb < 4) ? Wx_l : Wh_l;
    const float* Vbase = (kb < 4) ? x_src : h_src;
    const int kofs = (kb & 3) * 256;

    const int c16 = lane & 15;
    const int quad = lane >> 4;       // 0..3
    const int ncol = nb * 16 + c16;

    const float* wlane = Wbase + (size_t)ncol * 1024 + kofs + quad * 8;
    const float* alane = Vbase + (size_t)c16 * 1024 + kofs + quad * 8;

    // batch the ENTIRE 16KB W tile: 16 independent dwordx4 loads per lane
    float4 wbuf[16];
    #pragma unroll
    for (int i = 0; i < 16; ++i)
        wbuf[i] = *(const float4*)(wlane + (i >> 1) * 32 + (i & 1) * 4);

    floatx4 acc[4] = {{0.f,0.f,0.f,0.f},{0.f,0.f,0.f,0.f},
                      {0.f,0.f,0.f,0.f},{0.f,0.f,0.f,0.f}};

    #pragma unroll
    for (int ks = 0; ks < 8; ++ks) {
        float4 a0[4], a1[4];
        #pragma unroll
        for (int sub = 0; sub < 4; ++sub) {
            const float* vp = alane + (size_t)sub * 16 * 1024 + ks * 32;
            a0[sub] = *(const float4*)(vp);
            a1[sub] = *(const float4*)(vp + 4);
        }
        bf16x8 bfrag = cvt_bf16x8(wbuf[ks * 2], wbuf[ks * 2 + 1]);
        #pragma unroll
        for (int sub = 0; sub < 4; ++sub) {
            bf16x8 afrag = cvt_bf16x8(a0[sub], a1[sub]);
            acc[sub] = __builtin_amdgcn_mfma_f32_16x16x32_bf16(afrag, bfrag, acc[sub], 0, 0, 0);
        }
    }

    float* pdst = part + (size_t)kb * 64 * 4096;
    #pragma unroll
    for (int sub = 0; sub < 4; ++sub) {
        #pragma unroll
        for (int r = 0; r < 4; ++r) {
            int m = sub * 16 + quad * 4 + r;   // batch index
            pdst[(size_t)m * 4096 + ncol] = acc[sub][r];
        }
    }

    // ---- t role: 4 dots of the 8192 (which,g,b,r) dots per wave ----
    {
        const int which = gid >> 10;
        const int g = (gid >> 8) & 3;
        const int b = (gid >> 2) & 63;
        const int r0 = (gid & 3) * 4;
        const float* v = (which ? h_src : x_src) + (size_t)b * 1024;
        const float* Abase = (which ? A_h_l : A_x_l) + (size_t)g * R_ * 1024;
        float* tdst = (which ? t_h : t_x) + (size_t)(g * B_ + b) * R_;

        float vreg[16];
        #pragma unroll
        for (int i = 0; i < 16; ++i) vreg[i] = v[lane + 64 * i];

        #pragma unroll
        for (int j = 0; j < 4; ++j) {
            const float* a = Abase + (size_t)(r0 + j) * 1024;
            float s = 0.f;
            #pragma unroll
            for (int i = 0; i < 16; ++i) s += vreg[i] * a[lane + 64 * i];
            #pragma unroll
            for (int off = 32; off > 0; off >>= 1) s += __shfl_down(s, off);
            if (lane == 0) tdst[r0 + j] = s;
        }
    }
}

// ---------------------------------------------------------------------------
// Stage B: reduce partials + bias + LoRA + activations.
//   512 blocks x first 128 threads each -> 65536 elements, 1 per thread.
// ---------------------------------------------------------------------------
__device__ inline void cell_stage(
    const float* __restrict__ part,
    const float* __restrict__ bx_l, const float* __restrict__ bh_l,
    const float* __restrict__ Bx_l, const float* __restrict__ Bh_l,
    const float* __restrict__ t_x, const float* __restrict__ t_h,
    const float* __restrict__ c0_l,
    float* __restrict__ h_out, float* __restrict__ c_out,
    float* __restrict__ out_final)
{
    if (threadIdx.x >= 128) return;
    int idx = blockIdx.x * 128 + threadIdx.x;   // 0..65535
    int b = idx >> 10;
    int h = idx & 1023;

    float pre[4];
    #pragma unroll
    for (int g = 0; g < 4; ++g) {
        int n = g * 1024 + h;
        float s = bx_l[n] + bh_l[n];
        #pragma unroll
        for (int kk = 0; kk < 8; ++kk)
            s += part[(size_t)kk * 262144 + (size_t)b * 4096 + n];
        const float4* Bx4 = (const float4*)(Bx_l + (size_t)n * 16);
        const float4* Bh4 = (const float4*)(Bh_l + (size_t)n * 16);
        const float4* tx4 = (const float4*)(t_x + (size_t)(g * 64 + b) * 16);
        const float4* th4 = (const float4*)(t_h + (size_t)(g * 64 + b) * 16);
        #pragma unroll
        for (int q = 0; q < 4; ++q) {
            float4 bx = Bx4[q], tx = tx4[q];
            s += bx.x * tx.x + bx.y * tx.y + bx.z * tx.z + bx.w * tx.w;
            float4 bh = Bh4[q], th = th4[q];
            s += bh.x * th.x + bh.y * th.y + bh.z * th.z + bh.w * th.w;
        }
        pre[g] = s;
    }

    float it = 1.f / (1.f + __expf(-pre[0]));
    float ft = 1.f / (1.f + __expf(-pre[1]));
    float gt = tanhf(pre[2]);
    float ot = 1.f / (1.f + __expf(-pre[3]));
    float c = ft * c0_l[idx] + it * gt;
    float hn = ot * tanhf(c);

    h_out[idx] = hn;
    c_out[idx] = c;
    if (out_final) out_final[idx] = hn;
}

// ---------------------------------------------------------------------------
// Single NORMAL-launch kernel with manual grid barriers.
// 512 blocks x 256 threads; __launch_bounds__(256,2) caps VGPR at 256 so
// worst-case occupancy is 2 blocks/CU -> all 512 blocks co-resident.
// ---------------------------------------------------------------------------
__global__ __launch_bounds__(256, 2) void fused_kernel(
    const float* __restrict__ input_seq, const float* __restrict__ h0,
    const float* __restrict__ c0,
    const float* __restrict__ W_x, const float* __restrict__ W_h,
    const float* __restrict__ b_x, const float* __restrict__ b_h,
    const float* __restrict__ A_x, const float* __restrict__ B_x,
    const float* __restrict__ A_h, const float* __restrict__ B_h,
    float* __restrict__ out, unsigned* __restrict__ bar,
    float* __restrict__ part, float* __restrict__ t_x, float* __restrict__ t_h)
{
    // ---- barrier init: counters are poison (0xAA..) on entry ----
    if (blockIdx.x == 0) {
        if (threadIdx.x < 4) bar[threadIdx.x] = 0u;
        __syncthreads();
        if (threadIdx.x == 0) {
            __threadfence();
            __hip_atomic_store(bar + 4, BAR_MAGIC, __ATOMIC_RELEASE,
                               __HIP_MEMORY_SCOPE_AGENT);
        }
    } else {
        if (threadIdx.x == 0) {
            while (__hip_atomic_load(bar + 4, __ATOMIC_ACQUIRE,
                                     __HIP_MEMORY_SCOPE_AGENT) != BAR_MAGIC) {
                __builtin_amdgcn_s_sleep(1);
            }
        }
    }
    __syncthreads();

    float* h_t = out + B_ * H_;
    float* c_t = h_t + L_ * B_ * H_;
    const int gid = blockIdx.x * 4 + (threadIdx.x >> 6);   // 0..2047
    const int lane = threadIdx.x & 63;
    const float* x0 = input_seq + (size_t)(T_ - 1) * B_ * I_;

    #pragma unroll
    for (int l = 0; l < L_; ++l) {
        const float* xs = (l == 0) ? x0 : h_t;             // layer-0 h for l=1
        const float* hs = h0 + (size_t)l * B_ * H_;

        gemm_stage(W_x + (size_t)l * G_ * H_ * I_,
                   W_h + (size_t)l * G_ * H_ * H_,
                   xs, hs,
                   A_x + (size_t)l * G_ * R_ * I_,
                   A_h + (size_t)l * G_ * R_ * H_,
                   part, t_x, t_h, gid, lane);

        grid_barrier(bar, l * 2);          // gemm done -> cell may read

        cell_stage(part,
                   b_x + (size_t)l * G_ * H_, b_h + (size_t)l * G_ * H_,
                   B_x + (size_t)l * G_ * H_ * R_, B_h + (size_t)l * G_ * H_ * R_,
                   t_x, t_h,
                   c0 + (size_t)l * B_ * H_,
                   h_t + (size_t)l * B_ * H_, c_t + (size_t)l * B_ * H_,
                   (l == L_ - 1) ? out : nullptr);

        if (l == 0)
            grid_barrier(bar, 1);          // cell l0 done -> gemm l1 may read h_t
    }
}

// ---------------------------------------------------------------------------
extern "C" void kernel_launch(void* const* d_in, const int* in_sizes, int n_in,
                              void* d_out, int out_size, void* d_ws, size_t ws_size,
                              hipStream_t stream) {
    const float* input_seq = (const float*)d_in[0];
    const float* h0  = (const float*)d_in[1];
    const float* c0  = (const float*)d_in[2];
    const float* W_x = (const float*)d_in[3];
    const float* W_h = (const float*)d_in[4];
    const float* b_x = (const float*)d_in[5];
    const float* b_h = (const float*)d_in[6];
    const float* A_x = (const float*)d_in[7];
    const float* B_x = (const float*)d_in[8];
    const float* A_h = (const float*)d_in[9];
    const float* B_h = (const float*)d_in[10];

    float* out = (float*)d_out;                 // [B,H] then h_t, c_t

    // ws layout: bar (256B @0) | t_x @16KB | t_h @32KB | part @64KB (8MB)
    char* ws = (char*)d_ws;
    unsigned* bar = (unsigned*)ws;
    float* t_x = (float*)(ws + 16 * 1024);
    float* t_h = (float*)(ws + 32 * 1024);
    float* part = (float*)(ws + 64 * 1024);     // [8][64][4096] fp32 = 8 MB

    fused_kernel<<<NBLOCKS, 256, 0, stream>>>(
        input_seq, h0, c0, W_x, W_h, b_x, b_h,
        A_x, B_x, A_h, B_h, out, bar, part, t_x, t_h);
}

// Round 6
// 205.522 us; speedup vs baseline: 2.0916x; 2.0916x over previous
//
#include <hip/hip_runtime.h>
#include <hip/hip_bf16.h>
#include <math.h>

// Problem constants (from reference)
#define T_ 256
#define B_ 64
#define I_ 1024
#define L_ 2
#define G_ 4
#define H_ 1024
#define R_ 16

#define KSPLIT 16           // 16 K-chunks of 128 (8 over x-side, 8 over h-side)
#define KCHUNK 128

typedef __bf16 bf16x8 __attribute__((ext_vector_type(8)));
typedef float floatx4 __attribute__((ext_vector_type(4)));

__device__ inline bf16x8 cvt_bf16x8(float4 a, float4 b) {
    bf16x8 r;
    r[0] = (__bf16)a.x; r[1] = (__bf16)a.y; r[2] = (__bf16)a.z; r[3] = (__bf16)a.w;
    r[4] = (__bf16)b.x; r[5] = (__bf16)b.y; r[6] = (__bf16)b.z; r[7] = (__bf16)b.w;
    return r;
}

// ---------------------------------------------------------------------------
// GEMM + t kernel. Grid (64, 17), block 256 (4 waves).
//   y = 0..15 : gemm role. kb = y. Block tile: N=64 (16 cols/wave), M=64,
//               K-chunk 128. X-slice staged once to LDS (bf16); W streamed
//               global->reg (8 batched dwordx4/lane = 8 KB/wave in flight).
//   y = 16    : t role. 256 waves cover 512 (which,g,b) groups, 16 r-dots each.
// ---------------------------------------------------------------------------
__global__ __launch_bounds__(256, 4) void gemm_t_kernel(
    const float* __restrict__ Wx_l,   // [G*H, 1024] fp32
    const float* __restrict__ Wh_l,   // [G*H, 1024] fp32
    const float* __restrict__ x_src,  // [B,1024] fp32 (layer input)
    const float* __restrict__ h_src,  // [B,1024] fp32 (h0[l])
    const float* __restrict__ A_x_l,  // [G,R,1024]
    const float* __restrict__ A_h_l,  // [G,R,1024]
    float* __restrict__ part,         // [16][64][4096] fp32 partials
    float* __restrict__ t_x,          // [G,B,R]
    float* __restrict__ t_h)          // [G,B,R]
{
    const int tid = threadIdx.x;
    const int wave = tid >> 6;
    const int lane = tid & 63;
    const int c16 = lane & 15;
    const int quad = lane >> 4;       // 0..3

    if (blockIdx.y < 16) {
        // ---------------- GEMM role ----------------
        const int kb = blockIdx.y;
        const int side = kb >> 3;                 // 0: x, 1: h
        const int kofs = (kb & 7) * KCHUNK;
        const float* Wbase = side ? Wh_l : Wx_l;
        const float* Vbase = side ? h_src : x_src;

        // X-slice to LDS: 64 rows x 128 k (bf16), row stride 144 (=288B, 16B-aligned)
        __shared__ __bf16 Xl[64][144];
        #pragma unroll
        for (int i = 0; i < 8; ++i) {
            int f = tid + i * 256;                // float4 index, 2048 total
            int row = f >> 5;                     // 32 float4 per row
            int c4 = f & 31;
            float4 v = *(const float4*)(Vbase + (size_t)row * 1024 + kofs + c4 * 4);
            union { __bf16 b[4]; unsigned long long u; } tmp;
            tmp.b[0] = (__bf16)v.x; tmp.b[1] = (__bf16)v.y;
            tmp.b[2] = (__bf16)v.z; tmp.b[3] = (__bf16)v.w;
            *(unsigned long long*)&Xl[row][c4 * 4] = tmp.u;
        }

        // W tile: batch all 8 dwordx4 per lane BEFORE the barrier (8 KB/wave
        // in flight; 16 waves/CU -> 128 KB/CU outstanding on the HBM stream)
        const int ncol = blockIdx.x * 64 + wave * 16 + c16;
        const float* wlane = Wbase + (size_t)ncol * 1024 + kofs + quad * 8;
        float4 wbuf[8];
        #pragma unroll
        for (int i = 0; i < 8; ++i)
            wbuf[i] = *(const float4*)(wlane + (i >> 1) * 32 + (i & 1) * 4);

        __syncthreads();

        floatx4 acc[4] = {{0.f,0.f,0.f,0.f},{0.f,0.f,0.f,0.f},
                          {0.f,0.f,0.f,0.f},{0.f,0.f,0.f,0.f}};
        #pragma unroll
        for (int ks = 0; ks < 4; ++ks) {
            bf16x8 bfrag = cvt_bf16x8(wbuf[ks * 2], wbuf[ks * 2 + 1]);
            #pragma unroll
            for (int sub = 0; sub < 4; ++sub) {
                bf16x8 afrag = *(const bf16x8*)&Xl[sub * 16 + c16][ks * 32 + quad * 8];
                acc[sub] = __builtin_amdgcn_mfma_f32_16x16x32_bf16(afrag, bfrag, acc[sub], 0, 0, 0);
            }
        }

        float* pdst = part + (size_t)kb * 64 * 4096;
        #pragma unroll
        for (int sub = 0; sub < 4; ++sub) {
            #pragma unroll
            for (int r = 0; r < 4; ++r) {
                int m = sub * 16 + quad * 4 + r;   // batch index
                pdst[(size_t)m * 4096 + ncol] = acc[sub][r];
            }
        }
    } else {
        // ---------------- t role ----------------
        // 64 blocks x 4 waves = 256 waves; each covers 2 of 512 (which,g,b)
        const int widx = blockIdx.x * 4 + wave;
        #pragma unroll
        for (int gi = 0; gi < 2; ++gi) {
            const int grp = widx * 2 + gi;        // 0..511
            const int which = grp >> 8;
            const int g = (grp >> 6) & 3;
            const int b = grp & 63;
            const float* v = (which ? h_src : x_src) + (size_t)b * 1024;
            const float* Abase = (which ? A_h_l : A_x_l) + (size_t)g * R_ * 1024;
            float* tdst = (which ? t_h : t_x) + (size_t)(g * B_ + b) * R_;

            float vreg[16];
            #pragma unroll
            for (int i = 0; i < 16; ++i) vreg[i] = v[lane + 64 * i];

            for (int r = 0; r < R_; ++r) {
                const float* a = Abase + (size_t)r * 1024;
                float s = 0.f;
                #pragma unroll
                for (int i = 0; i < 16; ++i) s += vreg[i] * a[lane + 64 * i];
                #pragma unroll
                for (int off = 32; off > 0; off >>= 1) s += __shfl_down(s, off);
                if (lane == 0) tdst[r] = s;
            }
        }
    }
}

// ---------------------------------------------------------------------------
// Cell kernel: reduce 16 partials + bias + LoRA + activations
// ---------------------------------------------------------------------------
__global__ __launch_bounds__(256) void cell_kernel(
    const float* __restrict__ part,   // [16][64][4096]
    const float* __restrict__ bx_l,   // [G,H]
    const float* __restrict__ bh_l,   // [G,H]
    const float* __restrict__ Bx_l,   // [G,H,R]
    const float* __restrict__ Bh_l,   // [G,H,R]
    const float* __restrict__ t_x,    // [G,B,R]
    const float* __restrict__ t_h,    // [G,B,R]
    const float* __restrict__ c0_l,   // [B,H]
    float* __restrict__ h_out,        // [B,H]
    float* __restrict__ c_out,        // [B,H]
    float* __restrict__ out_final)    // [B,H] or nullptr
{
    int idx = blockIdx.x * 256 + threadIdx.x;   // 0..65535
    int b = idx >> 10;
    int h = idx & 1023;

    float pre[4];
    #pragma unroll
    for (int g = 0; g < 4; ++g) {
        int n = g * 1024 + h;
        float s = bx_l[n] + bh_l[n];
        #pragma unroll
        for (int kk = 0; kk < KSPLIT; ++kk)
            s += part[(size_t)kk * 262144 + (size_t)b * 4096 + n];
        const float4* Bx4 = (const float4*)(Bx_l + (size_t)n * 16);
        const float4* Bh4 = (const float4*)(Bh_l + (size_t)n * 16);
        const float4* tx4 = (const float4*)(t_x + (size_t)(g * 64 + b) * 16);
        const float4* th4 = (const float4*)(t_h + (size_t)(g * 64 + b) * 16);
        #pragma unroll
        for (int q = 0; q < 4; ++q) {
            float4 bx = Bx4[q], tx = tx4[q];
            s += bx.x * tx.x + bx.y * tx.y + bx.z * tx.z + bx.w * tx.w;
            float4 bh = Bh4[q], th = th4[q];
            s += bh.x * th.x + bh.y * th.y + bh.z * th.z + bh.w * th.w;
        }
        pre[g] = s;
    }

    float it = 1.f / (1.f + __expf(-pre[0]));
    float ft = 1.f / (1.f + __expf(-pre[1]));
    float gt = tanhf(pre[2]);
    float ot = 1.f / (1.f + __expf(-pre[3]));
    float c = ft * c0_l[idx] + it * gt;
    float hn = ot * tanhf(c);

    h_out[idx] = hn;
    c_out[idx] = c;
    if (out_final) out_final[idx] = hn;
}

// ---------------------------------------------------------------------------
extern "C" void kernel_launch(void* const* d_in, const int* in_sizes, int n_in,
                              void* d_out, int out_size, void* d_ws, size_t ws_size,
                              hipStream_t stream) {
    const float* input_seq = (const float*)d_in[0];
    const float* h0  = (const float*)d_in[1];
    const float* c0  = (const float*)d_in[2];
    const float* W_x = (const float*)d_in[3];
    const float* W_h = (const float*)d_in[4];
    const float* b_x = (const float*)d_in[5];
    const float* b_h = (const float*)d_in[6];
    const float* A_x = (const float*)d_in[7];
    const float* B_x = (const float*)d_in[8];
    const float* A_h = (const float*)d_in[9];
    const float* B_h = (const float*)d_in[10];

    float* out = (float*)d_out;                 // [B,H]
    float* h_t = out + B_ * H_;                 // [L,B,H]
    float* c_t = h_t + L_ * B_ * H_;            // [L,B,H]

    // ws layout: t_x @16KB | t_h @32KB | part @64KB ([16][64][4096] = 16 MB)
    char* ws = (char*)d_ws;
    float* t_x = (float*)(ws + 16 * 1024);
    float* t_h = (float*)(ws + 32 * 1024);
    float* part = (float*)(ws + 64 * 1024);

    const float* x_last = input_seq + (size_t)(T_ - 1) * B_ * I_;

    for (int l = 0; l < L_; ++l) {
        const float* x_src = (l == 0) ? x_last : (h_t + (size_t)(l - 1) * B_ * H_);
        const float* h_src = h0 + (size_t)l * B_ * H_;

        gemm_t_kernel<<<dim3(64, 17), 256, 0, stream>>>(
            W_x + (size_t)l * G_ * H_ * I_,
            W_h + (size_t)l * G_ * H_ * H_,
            x_src, h_src,
            A_x + (size_t)l * G_ * R_ * I_,
            A_h + (size_t)l * G_ * R_ * H_,
            part, t_x, t_h);

        cell_kernel<<<256, 256, 0, stream>>>(
            part,
            b_x + (size_t)l * G_ * H_, b_h + (size_t)l * G_ * H_,
            B_x + (size_t)l * G_ * H_ * R_, B_h + (size_t)l * G_ * H_ * R_,
            t_x, t_h,
            c0 + (size_t)l * B_ * H_,
            h_t + (size_t)l * B_ * H_, c_t + (size_t)l * B_ * H_,
            (l == L_ - 1) ? out : nullptr);
    }
}